// Round 1
// baseline (250.664 us; speedup 1.0000x reference)
//
#include <hip/hip_runtime.h>
#include <math.h>

// out[f,i,j] = X[f,i] + Y[f,j] + x[i,j]
//   idx[k] = (k - (W/2 - 0.5)) / (W*sqrt(2))
//   X[f,i] = (cos(a_f) - idx[i]) * cos(a_f) * 0.5
//   Y[f,j] = (sin(a_f) - idx[j]) * sin(a_f) * 0.5
// W=1024, F=64. Output 256 MiB fp32 -> HBM-write-bound.

#define W 1024
#define FCOUNT 64

__global__ __launch_bounds__(256) void dir_diagram_kernel(
    const float* __restrict__ x,
    const float* __restrict__ filters,
    float* __restrict__ out)
{
    // One block per (f, i) row. 64*1024 = 65536 blocks.
    const int bid = blockIdx.x;
    const int f = bid >> 10;        // bid / 1024
    const int i = bid & 1023;       // bid % 1024

    const float a = filters[f];     // wave-uniform load (L1/L2 hit)
    const float c = cosf(a);
    const float s = sinf(a);

    const float inv = 1.0f / (1024.0f * 1.41421356237309504880f); // 1/(W*sqrt(2))
    const float center = 511.5f;    // W/2 - 0.5

    const float idx_i = ((float)i - center) * inv;
    const float Xfi = (c - idx_i) * c * 0.5f;

    // Each thread writes one float4 of row (f, i).
    const int j0 = threadIdx.x << 2;            // 0..1020 step 4

    float4 xv = *reinterpret_cast<const float4*>(&x[i * W + j0]);

    float4 o;
    {
        float idx_j = ((float)(j0 + 0) - center) * inv;
        o.x = Xfi + (s - idx_j) * s * 0.5f + xv.x;
    }
    {
        float idx_j = ((float)(j0 + 1) - center) * inv;
        o.y = Xfi + (s - idx_j) * s * 0.5f + xv.y;
    }
    {
        float idx_j = ((float)(j0 + 2) - center) * inv;
        o.z = Xfi + (s - idx_j) * s * 0.5f + xv.z;
    }
    {
        float idx_j = ((float)(j0 + 3) - center) * inv;
        o.w = Xfi + (s - idx_j) * s * 0.5f + xv.w;
    }

    *reinterpret_cast<float4*>(&out[(size_t)f * (W * W) + (size_t)i * W + j0]) = o;
}

extern "C" void kernel_launch(void* const* d_in, const int* in_sizes, int n_in,
                              void* d_out, int out_size, void* d_ws, size_t ws_size,
                              hipStream_t stream) {
    const float* x       = (const float*)d_in[0];
    const float* filters = (const float*)d_in[1];
    float* out           = (float*)d_out;

    dim3 grid(FCOUNT * W);   // 65536 blocks
    dim3 block(256);         // one float4 per thread -> one row per block
    dir_diagram_kernel<<<grid, block, 0, stream>>>(x, filters, out);
}